// Round 2
// baseline (3359.888 us; speedup 1.0000x reference)
//
#include <hip/hip_runtime.h>

#define BB 16
#define NN 4096
#define DFEAT 20
#define SS 1024
#define KK 32
#define MM (BB*SS*KK)   // 524288

// ---- workspace layout (bytes), total ~73.6 MB ----
#define WS_STATS   0ull          // 8192   (1024 doubles: 3 layers x up to 256ch x {s1,s2})
#define WS_PARAMS  8192ull       // 4096   (floats: layer L at +L*256 floats: {mu,inv} per ch)
#define WS_FPSIDX  12288ull      // 65536
#define WS_CENT    81920ull      // 1572864  ([B*S][24] gathered combined rows)
#define WS_KNN     1654784ull    // 2097152  ([B*S][32] int)
#define WS_COMB    3751936ull    // 6291456  ([B*N][24] fp32, ch23 = 0 pad)
#define WS_YB      10043392ull   // 67108864 (bf16 [64][M]; y1 then overwritten in-place by y2)
#define WS_NEED    77152256ull

static __device__ __forceinline__ unsigned short f2bf(float f){
    unsigned u = __float_as_uint(f);
    unsigned r = (u + 0x7FFFu + ((u >> 16) & 1u)) >> 16;
    return (unsigned short)r;
}
static __device__ __forceinline__ float bf2f(unsigned short v){
    return __uint_as_float((unsigned)v << 16);
}

// ---------------------------------------------------------------------------
// 0) zero the stats area (replaces hipMemsetAsync; 1024 doubles)
// ---------------------------------------------------------------------------
__global__ void k_zstats(double* __restrict__ stats){
    int t = threadIdx.x;
#pragma unroll
    for (int i = 0; i < 4; ++i) stats[i*256 + t] = 0.0;
}

// fallback when ws is too small: zero d_out so the harness fails cleanly
__global__ void k_fail(float* __restrict__ out, int n){
    int i = blockIdx.x * 256 + threadIdx.x;
    if (i < n) out[i] = 0.f;
}

// ---------------------------------------------------------------------------
// 1) build combined [B][N][24] (ch23 = 0 pad)
// ---------------------------------------------------------------------------
__global__ __launch_bounds__(256) void k_build(const float* __restrict__ xyz,
                                               const float* __restrict__ feat,
                                               float* __restrict__ comb)
{
    int idx = blockIdx.x * 256 + threadIdx.x;   // over B*N = 65536
    int b = idx >> 12, j = idx & 4095;
    float c[24];
    c[0] = xyz[((size_t)b*3 + 0)*NN + j];
    c[1] = xyz[((size_t)b*3 + 1)*NN + j];
    c[2] = xyz[((size_t)b*3 + 2)*NN + j];
    const float* f = feat + ((size_t)b*NN + j)*DFEAT;
#pragma unroll
    for (int d = 0; d < 20; ++d) c[3+d] = f[d];
    c[23] = 0.f;
    float* out = comb + (size_t)idx * 24;
#pragma unroll
    for (int q = 0; q < 6; ++q)
        ((float4*)out)[q] = make_float4(c[4*q], c[4*q+1], c[4*q+2], c[4*q+3]);
}

// ---------------------------------------------------------------------------
// 2) FPS: one block per batch, 512 thr x 8 pts in regs; fp32 direct-form dists.
// ---------------------------------------------------------------------------
__global__ __launch_bounds__(512, 2) void k_fps(const float* __restrict__ comb,
                                                int* __restrict__ fpsidx)
{
    int b = blockIdx.x, t = threadIdx.x;
    const float* C = comb + (size_t)b * NN * 24;
    float pt[8][24];
    float dist[8];
#pragma unroll
    for (int p = 0; p < 8; ++p){
        const float4* r = (const float4*)(C + (size_t)(t + 512*p) * 24);
#pragma unroll
        for (int q = 0; q < 6; ++q){
            float4 v = r[q];
            pt[p][4*q] = v.x; pt[p][4*q+1] = v.y; pt[p][4*q+2] = v.z; pt[p][4*q+3] = v.w;
        }
        dist[p] = 1e10f;
    }
    __shared__ __align__(16) float cent[24];
    __shared__ unsigned long long wkey[8];
    __shared__ unsigned long long winner;
    if (t == 0){
#pragma unroll
        for (int q = 0; q < 24; ++q) cent[q] = pt[0][q];
    }
    __syncthreads();
    int far = 0;
    int lane = t & 63, w = t >> 6;
    for (int s = 0; s < SS; ++s){
        if (t == 0) fpsidx[b*SS + s] = far;
        float cc[24];
#pragma unroll
        for (int q = 0; q < 6; ++q){
            float4 v = ((const float4*)cent)[q];
            cc[4*q] = v.x; cc[4*q+1] = v.y; cc[4*q+2] = v.z; cc[4*q+3] = v.w;
        }
        unsigned long long best = 0;
#pragma unroll
        for (int p = 0; p < 8; ++p){
            float d0 = pt[p][0] - cc[0];
            float acc = d0 * d0;
#pragma unroll
            for (int q = 1; q < 23; ++q){
                float dd = pt[p][q] - cc[q];
                acc = fmaf(dd, dd, acc);
            }
            dist[p] = fminf(dist[p], acc);
            unsigned long long key = ((unsigned long long)__float_as_uint(dist[p]) << 32)
                                   | (unsigned long long)(0xFFFFFFFFu - (unsigned)(t + 512*p));
            best = best > key ? best : key;
        }
#pragma unroll
        for (int off = 32; off > 0; off >>= 1){
            unsigned long long o = __shfl_xor(best, off);
            best = best > o ? best : o;
        }
        if (lane == 0) wkey[w] = best;
        __syncthreads();
        if (t == 0){
            unsigned long long m = wkey[0];
#pragma unroll
            for (int i = 1; i < 8; ++i) m = m > wkey[i] ? m : wkey[i];
            winner = m;
        }
        __syncthreads();
        unsigned long long m = winner;
        int jw = (int)(0xFFFFFFFFu - (unsigned)(m & 0xFFFFFFFFull));
        far = jw;
        if ((jw & 511) == t){
            int p = jw >> 9;
#pragma unroll
            for (int pp = 0; pp < 8; ++pp) if (pp == p){
#pragma unroll
                for (int q = 0; q < 24; ++q) cent[q] = pt[pp][q];
            }
        }
        __syncthreads();
    }
}

// ---------------------------------------------------------------------------
// 3) gather centroids + outputs 0 and 2 (exact gathers)
// ---------------------------------------------------------------------------
__global__ __launch_bounds__(256) void k_gather(const float* __restrict__ comb,
                                                const int* __restrict__ fpsidx,
                                                float* __restrict__ cent,
                                                float* __restrict__ out0,
                                                float* __restrict__ out2)
{
    int idx = blockIdx.x * 256 + threadIdx.x;   // over B*S = 16384
    int b = idx >> 10, s = idx & 1023;
    int j = fpsidx[idx];
    const float* row = comb + ((size_t)b*NN + j) * 24;
    float* cr = cent + (size_t)idx * 24;
#pragma unroll
    for (int q = 0; q < 6; ++q) ((float4*)cr)[q] = ((const float4*)row)[q];
#pragma unroll
    for (int c = 0; c < 3; ++c) out0[((size_t)b*3 + c)*SS + s] = row[c];
    float* o2 = out2 + (size_t)idx * 20;
#pragma unroll
    for (int d = 0; d < 20; ++d) o2[d] = row[3 + d];
}

// ---------------------------------------------------------------------------
// 4) KNN: one wave per row; fp64 direct-form distances (pad ch contributes 0),
//    exact 32x (dist,idx) lexicographic min-extraction == stable argsort head.
// ---------------------------------------------------------------------------
__global__ __launch_bounds__(256) void k_knn(const float* __restrict__ comb,
                                             const float* __restrict__ cent,
                                             int* __restrict__ knn)
{
    int w = threadIdx.x >> 6, lane = threadIdx.x & 63;
    int r = blockIdx.x * 4 + w;     // row over B*S
    int b = r >> 10;
    const float* crow = cent + (size_t)r * 24;
    const float* P0 = comb + (size_t)b * NN * 24;
    double cc[24];
#pragma unroll
    for (int q = 0; q < 24; ++q) cc[q] = (double)crow[q];
    double d[64];
#pragma unroll
    for (int k = 0; k < 64; ++k){
        int j = k*64 + lane;
        const float4* pr = (const float4*)(P0 + (size_t)j * 24);
        double acc = 0.0;
#pragma unroll
        for (int q = 0; q < 6; ++q){
            float4 v = pr[q];
            double d0 = (double)v.x - cc[4*q];
            double d1 = (double)v.y - cc[4*q+1];
            double d2 = (double)v.z - cc[4*q+2];
            double d3 = (double)v.w - cc[4*q+3];
            acc += d0*d0; acc += d1*d1; acc += d2*d2; acc += d3*d3;
        }
        d[k] = acc;
    }
    int* orow = knn + (size_t)r * KK;
    for (int it = 0; it < KK; ++it){
        double dm = d[0]; int km = 0;
#pragma unroll
        for (int k = 1; k < 64; ++k){
            if (d[k] < dm){ dm = d[k]; km = k; }
        }
        int gi = km*64 + lane;
#pragma unroll
        for (int off = 32; off > 0; off >>= 1){
            double od = __shfl_xor(dm, off);
            int og = __shfl_xor(gi, off);
            if (od < dm || (od == dm && og < gi)){ dm = od; gi = og; }
        }
        int g = __builtin_amdgcn_readfirstlane(gi);
        if (lane == 0) orow[it] = g;
        int wk = g >> 6, wl = g & 63;
#pragma unroll
        for (int k = 0; k < 64; ++k)
            if (k == wk && lane == wl) d[k] = 1e300;
    }
}

// ---------------------------------------------------------------------------
// 5) layer 1: gather+normalize -> 24ch, GEMM 24->64, +bias -> yb bf16 [64][M]
// ---------------------------------------------------------------------------
__global__ __launch_bounds__(256) void k_l1(const float* __restrict__ comb,
                                            const float* __restrict__ cent,
                                            const int* __restrict__ knn,
                                            const float* __restrict__ w0,
                                            const float* __restrict__ b0,
                                            unsigned short* __restrict__ yb)
{
    __shared__ float Wt[24][64];
    __shared__ float Xt[24][68];
    int t = threadIdx.x;
    int m_base = blockIdx.x * 64;
    for (int i = t; i < 1536; i += 256){
        int o = i / 24, c = i - o*24;
        Wt[c][o] = w0[i];
    }
    {
        int sm = t & 63, g = t >> 6;
        int m = m_base + sm;
        int b = m >> 15;
        int row = m >> 5;
        int j = knn[m];
        const float* P  = comb + ((size_t)b*NN + j) * 24;
        const float* Cc = cent + (size_t)row * 24;
        if (g == 0){
            float dx = P[0]-Cc[0], dy = P[1]-Cc[1], dz = P[2]-Cc[2];
            Xt[0][sm] = dx; Xt[1][sm] = dy; Xt[2][sm] = dz;
            float n2 = dx*dx; n2 = fmaf(dy, dy, n2); n2 = fmaf(dz, dz, n2);
            Xt[3][sm] = sqrtf(fmaxf(n2, 1e-12f));
            Xt[4][sm] = P[3] - Cc[3];
            Xt[5][sm] = P[4] - Cc[4];
        } else {
#pragma unroll
            for (int cq = 0; cq < 6; ++cq){
                int c = 6*g + cq;
                Xt[c][sm] = P[c-1] - Cc[c-1];
            }
        }
    }
    __syncthreads();
    int i = t >> 4, jj = t & 15;
    float acc[4][4] = {};
#pragma unroll
    for (int c = 0; c < 24; ++c){
        float4 wv = *(const float4*)&Wt[c][i*4];
        float4 xv = *(const float4*)&Xt[c][jj*4];
        float wr[4] = {wv.x, wv.y, wv.z, wv.w};
        float xr[4] = {xv.x, xv.y, xv.z, xv.w};
#pragma unroll
        for (int a = 0; a < 4; ++a)
#pragma unroll
            for (int q = 0; q < 4; ++q) acc[a][q] = fmaf(wr[a], xr[q], acc[a][q]);
    }
#pragma unroll
    for (int oi = 0; oi < 4; ++oi){
        int o = i*4 + oi;
        float bb = b0[o];
        ushort4 rv;
        rv.x = f2bf(acc[oi][0]+bb); rv.y = f2bf(acc[oi][1]+bb);
        rv.z = f2bf(acc[oi][2]+bb); rv.w = f2bf(acc[oi][3]+bb);
        *(ushort4*)&yb[(size_t)o*MM + m_base + jj*4] = rv;
    }
}

// ---------------------------------------------------------------------------
// 6) per-channel sum/sumsq (fp64) over bf16 [64][M]
// ---------------------------------------------------------------------------
__global__ __launch_bounds__(256) void k_stats(const unsigned short* __restrict__ y,
                                               double* __restrict__ stats)
{
    const int chunks = 8;
    int c = blockIdx.x / chunks, ch = blockIdx.x % chunks;
    size_t base = (size_t)c * MM + (size_t)ch * (MM / chunks);
    double s1 = 0.0, s2 = 0.0;
    const unsigned short* p = y + base;
    for (int i = threadIdx.x; i < MM/chunks; i += 256){
        float v = bf2f(p[i]);
        s1 += v; s2 += (double)v * v;
    }
#pragma unroll
    for (int off = 32; off > 0; off >>= 1){
        s1 += __shfl_xor(s1, off);
        s2 += __shfl_xor(s2, off);
    }
    __shared__ double ps1[4], ps2[4];
    int w = threadIdx.x >> 6, lane = threadIdx.x & 63;
    if (lane == 0){ ps1[w] = s1; ps2[w] = s2; }
    __syncthreads();
    if (threadIdx.x == 0){
        atomicAdd(&stats[c*2 + 0], ps1[0]+ps1[1]+ps1[2]+ps1[3]);
        atomicAdd(&stats[c*2 + 1], ps2[0]+ps2[1]+ps2[2]+ps2[3]);
    }
}

__global__ void k_affine(const double* __restrict__ stats, float* __restrict__ params, int C)
{
    int c = threadIdx.x;
    if (c < C){
        double mu = stats[c*2] / (double)MM;
        double var = stats[c*2 + 1] / (double)MM - mu*mu;
        params[c*2 + 0] = (float)mu;
        params[c*2 + 1] = (float)(1.0 / sqrt(var + 1e-5));
    }
}

// ---------------------------------------------------------------------------
// 7) layer 2 IN-PLACE: bn1+relu(yb) -> GEMM 64->64 -> yb (same tile, bf16)
// ---------------------------------------------------------------------------
__global__ __launch_bounds__(256) void k_l2(unsigned short* __restrict__ yb,
                                            const float* __restrict__ prm,
                                            const float* __restrict__ gg,
                                            const float* __restrict__ bt,
                                            const float* __restrict__ w,
                                            const float* __restrict__ bias)
{
    __shared__ float Wt[64][64];
    __shared__ float Xt[64][68];
    int t = threadIdx.x;
    int m_base = blockIdx.x * 64;
    for (int i = t; i < 4096; i += 256){
        int o = i >> 6, c = i & 63;
        Wt[c][o] = w[i];
    }
#pragma unroll
    for (int rp = 0; rp < 16; ++rp){
        int idx = rp*256 + t;
        int c = idx >> 6, mm2 = idx & 63;
        float v = bf2f(yb[(size_t)c*MM + m_base + mm2]);
        float t1 = (v - prm[c*2]) * prm[c*2 + 1];
        Xt[c][mm2] = fmaxf(fmaf(t1, gg[c], bt[c]), 0.f);
    }
    __syncthreads();
    int i = t >> 4, jj = t & 15;
    float acc[4][4] = {};
#pragma unroll
    for (int c = 0; c < 64; ++c){
        float4 wv = *(const float4*)&Wt[c][i*4];
        float4 xv = *(const float4*)&Xt[c][jj*4];
        float wr[4] = {wv.x, wv.y, wv.z, wv.w};
        float xr[4] = {xv.x, xv.y, xv.z, xv.w};
#pragma unroll
        for (int a = 0; a < 4; ++a)
#pragma unroll
            for (int q = 0; q < 4; ++q) acc[a][q] = fmaf(wr[a], xr[q], acc[a][q]);
    }
    // all reads of this tile happened before the barrier above -> in-place safe
#pragma unroll
    for (int oi = 0; oi < 4; ++oi){
        int o = i*4 + oi;
        float bb = bias[o];
        ushort4 rv;
        rv.x = f2bf(acc[oi][0]+bb); rv.y = f2bf(acc[oi][1]+bb);
        rv.z = f2bf(acc[oi][2]+bb); rv.w = f2bf(acc[oi][3]+bb);
        *(ushort4*)&yb[(size_t)o*MM + m_base + jj*4] = rv;
    }
}

// ---------------------------------------------------------------------------
// 8) layer 3 stats pass: bn2+relu(yb) -> GEMM 64->128 in regs -> stats3 only
//    (y3 never stored; final pass recomputes identically)
// ---------------------------------------------------------------------------
__global__ __launch_bounds__(256) void k_l3s(const unsigned short* __restrict__ yb,
                                             const float* __restrict__ prm,
                                             const float* __restrict__ gg,
                                             const float* __restrict__ bt,
                                             const float* __restrict__ w,
                                             const float* __restrict__ bias,
                                             double* __restrict__ stats)
{
    __shared__ float Wt[64][128];
    __shared__ float Xt[64][68];
    int t = threadIdx.x;
    for (int i = t; i < 8192; i += 256){
        int o = i >> 6, c = i & 63;
        Wt[c][o] = w[i];
    }
    int i = t >> 4, jj = t & 15;
    double s1[8] = {}, s2[8] = {};
    for (int tt = 0; tt < 16; ++tt){
        int m_base = (blockIdx.x * 16 + tt) * 64;
        __syncthreads();
#pragma unroll
        for (int rp = 0; rp < 16; ++rp){
            int idx = rp*256 + t;
            int c = idx >> 6, mm2 = idx & 63;
            float v = bf2f(yb[(size_t)c*MM + m_base + mm2]);
            float t1 = (v - prm[c*2]) * prm[c*2 + 1];
            Xt[c][mm2] = fmaxf(fmaf(t1, gg[c], bt[c]), 0.f);
        }
        __syncthreads();
        float acc[8][4] = {};
#pragma unroll
        for (int c = 0; c < 64; ++c){
            float4 w0v = *(const float4*)&Wt[c][i*8];
            float4 w1v = *(const float4*)&Wt[c][i*8 + 4];
            float4 xv  = *(const float4*)&Xt[c][jj*4];
            float wr[8] = {w0v.x, w0v.y, w0v.z, w0v.w, w1v.x, w1v.y, w1v.z, w1v.w};
            float xr[4] = {xv.x, xv.y, xv.z, xv.w};
#pragma unroll
            for (int a = 0; a < 8; ++a)
#pragma unroll
                for (int q = 0; q < 4; ++q) acc[a][q] = fmaf(wr[a], xr[q], acc[a][q]);
        }
#pragma unroll
        for (int oi = 0; oi < 8; ++oi){
            float bb = bias[i*8 + oi];
#pragma unroll
            for (int q = 0; q < 4; ++q){
                float v = acc[oi][q] + bb;
                s1[oi] += v;
                s2[oi] += (double)v * v;
            }
        }
    }
#pragma unroll
    for (int oi = 0; oi < 8; ++oi){
#pragma unroll
        for (int off = 1; off < 16; off <<= 1){
            s1[oi] += __shfl_xor(s1[oi], off);
            s2[oi] += __shfl_xor(s2[oi], off);
        }
    }
    if (jj == 0){
#pragma unroll
        for (int oi = 0; oi < 8; ++oi){
            int o = i*8 + oi;
            atomicAdd(&stats[o*2 + 0], s1[oi]);
            atomicAdd(&stats[o*2 + 1], s2[oi]);
        }
    }
}

// ---------------------------------------------------------------------------
// 9) final: recompute layer3 GEMM, bn3+relu, max over K -> out1 [B][128][S]
// ---------------------------------------------------------------------------
__global__ __launch_bounds__(256) void k_final(const unsigned short* __restrict__ yb,
                                               const float* __restrict__ prm2,
                                               const float* __restrict__ g1c,
                                               const float* __restrict__ bt1c,
                                               const float* __restrict__ w,
                                               const float* __restrict__ bias,
                                               const float* __restrict__ prm3,
                                               const float* __restrict__ g2c,
                                               const float* __restrict__ bt2c,
                                               float* __restrict__ out1)
{
    __shared__ float Wt[64][128];
    __shared__ float Xt[64][68];
    int t = threadIdx.x;
    int m_base = blockIdx.x * 64;
    for (int i = t; i < 8192; i += 256){
        int o = i >> 6, c = i & 63;
        Wt[c][o] = w[i];
    }
#pragma unroll
    for (int rp = 0; rp < 16; ++rp){
        int idx = rp*256 + t;
        int c = idx >> 6, mm2 = idx & 63;
        float v = bf2f(yb[(size_t)c*MM + m_base + mm2]);
        float t1 = (v - prm2[c*2]) * prm2[c*2 + 1];
        Xt[c][mm2] = fmaxf(fmaf(t1, g1c[c], bt1c[c]), 0.f);
    }
    __syncthreads();
    int i = t >> 4, jj = t & 15;
    float acc[8][4] = {};
#pragma unroll
    for (int c = 0; c < 64; ++c){
        float4 w0v = *(const float4*)&Wt[c][i*8];
        float4 w1v = *(const float4*)&Wt[c][i*8 + 4];
        float4 xv  = *(const float4*)&Xt[c][jj*4];
        float wr[8] = {w0v.x, w0v.y, w0v.z, w0v.w, w1v.x, w1v.y, w1v.z, w1v.w};
        float xr[4] = {xv.x, xv.y, xv.z, xv.w};
#pragma unroll
        for (int a = 0; a < 8; ++a)
#pragma unroll
            for (int q = 0; q < 4; ++q) acc[a][q] = fmaf(wr[a], xr[q], acc[a][q]);
    }
    float mx[8];
#pragma unroll
    for (int oi = 0; oi < 8; ++oi){
        int o = i*8 + oi;
        float bb = bias[o];
        float mu = prm3[o*2], inv = prm3[o*2 + 1], gv = g2c[o], bv = bt2c[o];
        float m = 0.f;   // relu'd values >= 0
#pragma unroll
        for (int q = 0; q < 4; ++q){
            float v = acc[oi][q] + bb;
            float r = fmaxf(fmaf((v - mu) * inv, gv, bv), 0.f);
            m = fmaxf(m, r);
        }
        mx[oi] = m;
    }
#pragma unroll
    for (int oi = 0; oi < 8; ++oi){
#pragma unroll
        for (int off = 1; off < 8; off <<= 1)
            mx[oi] = fmaxf(mx[oi], __shfl_xor(mx[oi], off));
    }
    if ((jj & 7) == 0){
        int rg = (m_base >> 5) + (jj >> 3);   // global row b*S+s
        int b = rg >> 10, s = rg & 1023;
#pragma unroll
        for (int oi = 0; oi < 8; ++oi)
            out1[(size_t)b*131072 + (size_t)(i*8 + oi)*1024 + s] = mx[oi];
    }
}

// ---------------------------------------------------------------------------
extern "C" void kernel_launch(void* const* d_in, const int* in_sizes, int n_in,
                              void* d_out, int out_size, void* d_ws, size_t ws_size,
                              hipStream_t stream)
{
    const float* xyz  = (const float*)d_in[0];
    const float* feat = (const float*)d_in[1];
    const float* w0 = (const float*)d_in[2];  const float* b0  = (const float*)d_in[3];
    const float* g0 = (const float*)d_in[4];  const float* bt0 = (const float*)d_in[5];
    const float* w1 = (const float*)d_in[6];  const float* b1  = (const float*)d_in[7];
    const float* g1 = (const float*)d_in[8];  const float* bt1 = (const float*)d_in[9];
    const float* w2 = (const float*)d_in[10]; const float* b2  = (const float*)d_in[11];
    const float* g2 = (const float*)d_in[12]; const float* bt2 = (const float*)d_in[13];

    float* out0 = (float*)d_out;
    float* out1 = (float*)d_out + 49152;
    float* out2 = (float*)d_out + 49152 + 2097152;

    if (ws_size < WS_NEED){
        // workspace too small for this design: fail measurably, not with a fault
        k_fail<<<(out_size + 255)/256, 256, 0, stream>>>((float*)d_out, out_size);
        return;
    }

    char* ws = (char*)d_ws;
    double* stats = (double*)(ws + WS_STATS);
    float* params = (float*)(ws + WS_PARAMS);
    int*   fpsidx = (int*)(ws + WS_FPSIDX);
    float* cent   = (float*)(ws + WS_CENT);
    int*   knn    = (int*)(ws + WS_KNN);
    float* comb   = (float*)(ws + WS_COMB);
    unsigned short* yb = (unsigned short*)(ws + WS_YB);

    k_zstats<<<1,    256, 0, stream>>>(stats);
    k_build <<<256,  256, 0, stream>>>(xyz, feat, comb);
    k_fps   <<<16,   512, 0, stream>>>(comb, fpsidx);
    k_gather<<<64,   256, 0, stream>>>(comb, fpsidx, cent, out0, out2);
    k_knn   <<<4096, 256, 0, stream>>>(comb, cent, knn);
    k_l1    <<<8192, 256, 0, stream>>>(comb, cent, knn, w0, b0, yb);
    k_stats <<<512,  256, 0, stream>>>(yb, stats);
    k_affine<<<1,    128, 0, stream>>>(stats, params, 64);
    k_l2    <<<8192, 256, 0, stream>>>(yb, params, g0, bt0, w1, b1);
    k_stats <<<512,  256, 0, stream>>>(yb, stats + 256);
    k_affine<<<1,    128, 0, stream>>>(stats + 256, params + 256, 64);
    k_l3s   <<<512,  256, 0, stream>>>(yb, params + 256, g1, bt1, w2, b2, stats + 512);
    k_affine<<<1,    128, 0, stream>>>(stats + 512, params + 512, 128);
    k_final <<<8192, 256, 0, stream>>>(yb, params + 256, g1, bt1, w2, b2,
                                       params + 512, g2, bt2, out1);
}

// Round 4
// 3052.923 us; speedup vs baseline: 1.1005x; 1.1005x over previous
//
#include <hip/hip_runtime.h>

#define BB 16
#define NN 4096
#define DFEAT 20
#define SS 1024
#define KK 32
#define MM (BB*SS*KK)   // 524288

// ---- workspace layout (bytes), total ~73.6 MB ----
#define WS_STATS   0ull          // 8192   (1024 doubles: 3 layers x up to 256ch x {s1,s2})
#define WS_PARAMS  8192ull       // 4096   (floats: layer L at +L*256 floats: {mu,inv} per ch)
#define WS_FPSIDX  12288ull      // 65536
#define WS_CENT    81920ull      // 1572864  ([B*S][24] gathered combined rows)
#define WS_KNN     1654784ull    // 2097152  ([B*S][32] int)
#define WS_COMB    3751936ull    // 6291456  ([B*N][24] fp32, ch23 = 0 pad)
#define WS_YB      10043392ull   // 67108864 (bf16 [64][M]; y1 then overwritten in-place by y2)
#define WS_NEED    77152256ull

static __device__ __forceinline__ unsigned short f2bf(float f){
    unsigned u = __float_as_uint(f);
    unsigned r = (u + 0x7FFFu + ((u >> 16) & 1u)) >> 16;
    return (unsigned short)r;
}
static __device__ __forceinline__ float bf2f(unsigned short v){
    return __uint_as_float((unsigned)v << 16);
}

// ---------------------------------------------------------------------------
// 0) zero the stats area (1024 doubles)
// ---------------------------------------------------------------------------
__global__ void k_zstats(double* __restrict__ stats){
    int t = threadIdx.x;
#pragma unroll
    for (int i = 0; i < 4; ++i) stats[i*256 + t] = 0.0;
}

// fallback when ws is too small: zero d_out so the harness fails cleanly
__global__ void k_fail(float* __restrict__ out, int n){
    int i = blockIdx.x * 256 + threadIdx.x;
    if (i < n) out[i] = 0.f;
}

// ---------------------------------------------------------------------------
// 1) build combined [B][N][24] (ch23 = 0 pad)
// ---------------------------------------------------------------------------
__global__ __launch_bounds__(256) void k_build(const float* __restrict__ xyz,
                                               const float* __restrict__ feat,
                                               float* __restrict__ comb)
{
    int idx = blockIdx.x * 256 + threadIdx.x;   // over B*N = 65536
    int b = idx >> 12, j = idx & 4095;
    float c[24];
    c[0] = xyz[((size_t)b*3 + 0)*NN + j];
    c[1] = xyz[((size_t)b*3 + 1)*NN + j];
    c[2] = xyz[((size_t)b*3 + 2)*NN + j];
    const float* f = feat + ((size_t)b*NN + j)*DFEAT;
#pragma unroll
    for (int d = 0; d < 20; ++d) c[3+d] = f[d];
    c[23] = 0.f;
    float* out = comb + (size_t)idx * 24;
#pragma unroll
    for (int q = 0; q < 6; ++q)
        ((float4*)out)[q] = make_float4(c[4*q], c[4*q+1], c[4*q+2], c[4*q+3]);
}

// ---------------------------------------------------------------------------
// 2) FPS v3: one barrier per iteration (R3 structure) with bit-exact R2
//    distance arithmetic (sequential fmaf over ch0..22 — ORDER IS LOAD-BEARING:
//    the R3 even/odd reassociation flipped an argmax and broke output 0).
//    Points re-read from L2 each iter (compiler rematerialized anyway in R2).
// ---------------------------------------------------------------------------
__global__ __launch_bounds__(512, 2) void k_fps(const float* __restrict__ comb,
                                                int* __restrict__ fpsidx)
{
    int b = blockIdx.x, t = threadIdx.x;
    const float* C = comb + (size_t)b * NN * 24;
    float dist[8];
#pragma unroll
    for (int p = 0; p < 8; ++p) dist[p] = 1e10f;
    __shared__ unsigned long long wkey[2][8];
    int lane = t & 63, w = t >> 6;
    int far = 0;
    for (int s = 0; s < SS; ++s){
        if (t == 0) fpsidx[b*SS + s] = far;
        const float4* crow = (const float4*)(C + (size_t)far * 24);
        float cc[24];
#pragma unroll
        for (int q = 0; q < 6; ++q){
            float4 cv = crow[q];          // uniform address: broadcast load
            cc[4*q] = cv.x; cc[4*q+1] = cv.y; cc[4*q+2] = cv.z; cc[4*q+3] = cv.w;
        }
        unsigned long long best = 0;
#pragma unroll
        for (int p = 0; p < 8; ++p){
            const float4* r = (const float4*)(C + (size_t)(t + 512*p) * 24);
            float pv[24];
#pragma unroll
            for (int q = 0; q < 6; ++q){
                float4 v = r[q];
                pv[4*q] = v.x; pv[4*q+1] = v.y; pv[4*q+2] = v.z; pv[4*q+3] = v.w;
            }
            float d0 = pv[0] - cc[0];
            float acc = d0 * d0;
#pragma unroll
            for (int q = 1; q < 23; ++q){
                float dd = pv[q] - cc[q];
                acc = fmaf(dd, dd, acc);
            }
            dist[p] = fminf(dist[p], acc);
            unsigned long long key = ((unsigned long long)__float_as_uint(dist[p]) << 32)
                                   | (unsigned long long)(0xFFFFFFFFu - (unsigned)(t + 512*p));
            best = best > key ? best : key;
        }
#pragma unroll
        for (int off = 32; off > 0; off >>= 1){
            unsigned long long o = __shfl_xor(best, off);
            best = best > o ? best : o;
        }
        int par = s & 1;
        if (lane == 0) wkey[par][w] = best;
        __syncthreads();
        // double-buffered: next write to this buffer is 2 iters (1 barrier) away
        unsigned long long k2 = wkey[par][lane & 7];
#pragma unroll
        for (int off = 1; off < 8; off <<= 1){
            unsigned long long o = __shfl_xor(k2, off);
            k2 = k2 > o ? k2 : o;
        }
        far = (int)(0xFFFFFFFFu - (unsigned)(k2 & 0xFFFFFFFFull));
    }
}

// ---------------------------------------------------------------------------
// 3) gather centroids + outputs 0 and 2 (exact gathers)
// ---------------------------------------------------------------------------
__global__ __launch_bounds__(256) void k_gather(const float* __restrict__ comb,
                                                const int* __restrict__ fpsidx,
                                                float* __restrict__ cent,
                                                float* __restrict__ out0,
                                                float* __restrict__ out2)
{
    int idx = blockIdx.x * 256 + threadIdx.x;   // over B*S = 16384
    int b = idx >> 10, s = idx & 1023;
    int j = fpsidx[idx];
    const float* row = comb + ((size_t)b*NN + j) * 24;
    float* cr = cent + (size_t)idx * 24;
#pragma unroll
    for (int q = 0; q < 6; ++q) ((float4*)cr)[q] = ((const float4*)row)[q];
#pragma unroll
    for (int c = 0; c < 3; ++c) out0[((size_t)b*3 + c)*SS + s] = row[c];
    float* o2 = out2 + (size_t)idx * 20;
#pragma unroll
    for (int d = 0; d < 20; ++d) o2[d] = row[3 + d];
}

// ---------------------------------------------------------------------------
// 4) KNN: one wave per row; fp64 direct-form distances, exact 32x (dist,idx)
//    lexicographic min-extraction == stable argsort head.
//    __launch_bounds__(256,1): 1 wave/EU -> 512-VGPR cap -> d[64] fp64 (128
//    VGPRs) + cc[24] fp64 (48) CANNOT spill to scratch (R2 spill suspect).
// ---------------------------------------------------------------------------
__global__ __launch_bounds__(256, 1) void k_knn(const float* __restrict__ comb,
                                                const float* __restrict__ cent,
                                                int* __restrict__ knn)
{
    int w = threadIdx.x >> 6, lane = threadIdx.x & 63;
    int r = blockIdx.x * 4 + w;     // row over B*S
    int b = r >> 10;
    const float* crow = cent + (size_t)r * 24;
    const float* P0 = comb + (size_t)b * NN * 24;
    double cc[24];
#pragma unroll
    for (int q = 0; q < 24; ++q) cc[q] = (double)crow[q];
    double d[64];
#pragma unroll
    for (int k = 0; k < 64; ++k){
        int j = k*64 + lane;
        const float4* pr = (const float4*)(P0 + (size_t)j * 24);
        double acc = 0.0;
#pragma unroll
        for (int q = 0; q < 6; ++q){
            float4 v = pr[q];
            double d0 = (double)v.x - cc[4*q];
            double d1 = (double)v.y - cc[4*q+1];
            double d2 = (double)v.z - cc[4*q+2];
            double d3 = (double)v.w - cc[4*q+3];
            acc += d0*d0; acc += d1*d1; acc += d2*d2; acc += d3*d3;
        }
        d[k] = acc;
    }
    int* orow = knn + (size_t)r * KK;
    for (int it = 0; it < KK; ++it){
        double dm = d[0]; int km = 0;
#pragma unroll
        for (int k = 1; k < 64; ++k){
            if (d[k] < dm){ dm = d[k]; km = k; }
        }
        int gi = km*64 + lane;
#pragma unroll
        for (int off = 32; off > 0; off >>= 1){
            double od = __shfl_xor(dm, off);
            int og = __shfl_xor(gi, off);
            if (od < dm || (od == dm && og < gi)){ dm = od; gi = og; }
        }
        int g = __builtin_amdgcn_readfirstlane(gi);
        if (lane == 0) orow[it] = g;
        int wk = g >> 6, wl = g & 63;
#pragma unroll
        for (int k = 0; k < 64; ++k)
            if (k == wk && lane == wl) d[k] = 1e300;
    }
}

// ---------------------------------------------------------------------------
// 5) layer 1: gather+normalize -> 24ch, GEMM 24->64, +bias -> yb bf16 [64][M]
// ---------------------------------------------------------------------------
__global__ __launch_bounds__(256) void k_l1(const float* __restrict__ comb,
                                            const float* __restrict__ cent,
                                            const int* __restrict__ knn,
                                            const float* __restrict__ w0,
                                            const float* __restrict__ b0,
                                            unsigned short* __restrict__ yb)
{
    __shared__ float Wt[24][64];
    __shared__ float Xt[24][68];
    int t = threadIdx.x;
    int m_base = blockIdx.x * 64;
    for (int i = t; i < 1536; i += 256){
        int o = i / 24, c = i - o*24;
        Wt[c][o] = w0[i];
    }
    {
        int sm = t & 63, g = t >> 6;
        int m = m_base + sm;
        int b = m >> 15;
        int row = m >> 5;
        int j = knn[m];
        const float* P  = comb + ((size_t)b*NN + j) * 24;
        const float* Cc = cent + (size_t)row * 24;
        if (g == 0){
            float dx = P[0]-Cc[0], dy = P[1]-Cc[1], dz = P[2]-Cc[2];
            Xt[0][sm] = dx; Xt[1][sm] = dy; Xt[2][sm] = dz;
            float n2 = dx*dx; n2 = fmaf(dy, dy, n2); n2 = fmaf(dz, dz, n2);
            Xt[3][sm] = sqrtf(fmaxf(n2, 1e-12f));
            Xt[4][sm] = P[3] - Cc[3];
            Xt[5][sm] = P[4] - Cc[4];
        } else {
#pragma unroll
            for (int cq = 0; cq < 6; ++cq){
                int c = 6*g + cq;
                Xt[c][sm] = P[c-1] - Cc[c-1];
            }
        }
    }
    __syncthreads();
    int i = t >> 4, jj = t & 15;
    float acc[4][4] = {};
#pragma unroll
    for (int c = 0; c < 24; ++c){
        float4 wv = *(const float4*)&Wt[c][i*4];
        float4 xv = *(const float4*)&Xt[c][jj*4];
        float wr[4] = {wv.x, wv.y, wv.z, wv.w};
        float xr[4] = {xv.x, xv.y, xv.z, xv.w};
#pragma unroll
        for (int a = 0; a < 4; ++a)
#pragma unroll
            for (int q = 0; q < 4; ++q) acc[a][q] = fmaf(wr[a], xr[q], acc[a][q]);
    }
#pragma unroll
    for (int oi = 0; oi < 4; ++oi){
        int o = i*4 + oi;
        float bb = b0[o];
        ushort4 rv;
        rv.x = f2bf(acc[oi][0]+bb); rv.y = f2bf(acc[oi][1]+bb);
        rv.z = f2bf(acc[oi][2]+bb); rv.w = f2bf(acc[oi][3]+bb);
        *(ushort4*)&yb[(size_t)o*MM + m_base + jj*4] = rv;
    }
}

// ---------------------------------------------------------------------------
// 6) per-channel sum/sumsq (fp64) over bf16 [64][M]
// ---------------------------------------------------------------------------
__global__ __launch_bounds__(256) void k_stats(const unsigned short* __restrict__ y,
                                               double* __restrict__ stats)
{
    const int chunks = 8;
    int c = blockIdx.x / chunks, ch = blockIdx.x % chunks;
    size_t base = (size_t)c * MM + (size_t)ch * (MM / chunks);
    double s1 = 0.0, s2 = 0.0;
    const unsigned short* p = y + base;
    for (int i = threadIdx.x; i < MM/chunks; i += 256){
        float v = bf2f(p[i]);
        s1 += v; s2 += (double)v * v;
    }
#pragma unroll
    for (int off = 32; off > 0; off >>= 1){
        s1 += __shfl_xor(s1, off);
        s2 += __shfl_xor(s2, off);
    }
    __shared__ double ps1[4], ps2[4];
    int w = threadIdx.x >> 6, lane = threadIdx.x & 63;
    if (lane == 0){ ps1[w] = s1; ps2[w] = s2; }
    __syncthreads();
    if (threadIdx.x == 0){
        atomicAdd(&stats[c*2 + 0], ps1[0]+ps1[1]+ps1[2]+ps1[3]);
        atomicAdd(&stats[c*2 + 1], ps2[0]+ps2[1]+ps2[2]+ps2[3]);
    }
}

__global__ void k_affine(const double* __restrict__ stats, float* __restrict__ params, int C)
{
    int c = threadIdx.x;
    if (c < C){
        double mu = stats[c*2] / (double)MM;
        double var = stats[c*2 + 1] / (double)MM - mu*mu;
        params[c*2 + 0] = (float)mu;
        params[c*2 + 1] = (float)(1.0 / sqrt(var + 1e-5));
    }
}

// ---------------------------------------------------------------------------
// 7) layer 2 IN-PLACE: bn1+relu(yb) -> GEMM 64->64 -> yb (same tile, bf16)
// ---------------------------------------------------------------------------
__global__ __launch_bounds__(256) void k_l2(unsigned short* __restrict__ yb,
                                            const float* __restrict__ prm,
                                            const float* __restrict__ gg,
                                            const float* __restrict__ bt,
                                            const float* __restrict__ w,
                                            const float* __restrict__ bias)
{
    __shared__ float Wt[64][64];
    __shared__ float Xt[64][68];
    int t = threadIdx.x;
    int m_base = blockIdx.x * 64;
    for (int i = t; i < 4096; i += 256){
        int o = i >> 6, c = i & 63;
        Wt[c][o] = w[i];
    }
#pragma unroll
    for (int rp = 0; rp < 16; ++rp){
        int idx = rp*256 + t;
        int c = idx >> 6, mm2 = idx & 63;
        float v = bf2f(yb[(size_t)c*MM + m_base + mm2]);
        float t1 = (v - prm[c*2]) * prm[c*2 + 1];
        Xt[c][mm2] = fmaxf(fmaf(t1, gg[c], bt[c]), 0.f);
    }
    __syncthreads();
    int i = t >> 4, jj = t & 15;
    float acc[4][4] = {};
#pragma unroll
    for (int c = 0; c < 64; ++c){
        float4 wv = *(const float4*)&Wt[c][i*4];
        float4 xv = *(const float4*)&Xt[c][jj*4];
        float wr[4] = {wv.x, wv.y, wv.z, wv.w};
        float xr[4] = {xv.x, xv.y, xv.z, xv.w};
#pragma unroll
        for (int a = 0; a < 4; ++a)
#pragma unroll
            for (int q = 0; q < 4; ++q) acc[a][q] = fmaf(wr[a], xr[q], acc[a][q]);
    }
    // all reads of this tile happened before the barrier above -> in-place safe
#pragma unroll
    for (int oi = 0; oi < 4; ++oi){
        int o = i*4 + oi;
        float bb = bias[o];
        ushort4 rv;
        rv.x = f2bf(acc[oi][0]+bb); rv.y = f2bf(acc[oi][1]+bb);
        rv.z = f2bf(acc[oi][2]+bb); rv.w = f2bf(acc[oi][3]+bb);
        *(ushort4*)&yb[(size_t)o*MM + m_base + jj*4] = rv;
    }
}

// ---------------------------------------------------------------------------
// 8) layer 3 stats pass: bn2+relu(yb) -> GEMM 64->128 in regs -> stats3 only
// ---------------------------------------------------------------------------
__global__ __launch_bounds__(256) void k_l3s(const unsigned short* __restrict__ yb,
                                             const float* __restrict__ prm,
                                             const float* __restrict__ gg,
                                             const float* __restrict__ bt,
                                             const float* __restrict__ w,
                                             const float* __restrict__ bias,
                                             double* __restrict__ stats)
{
    __shared__ float Wt[64][128];
    __shared__ float Xt[64][68];
    int t = threadIdx.x;
    for (int i = t; i < 8192; i += 256){
        int o = i >> 6, c = i & 63;
        Wt[c][o] = w[i];
    }
    int i = t >> 4, jj = t & 15;
    double s1[8] = {}, s2[8] = {};
    for (int tt = 0; tt < 16; ++tt){
        int m_base = (blockIdx.x * 16 + tt) * 64;
        __syncthreads();
#pragma unroll
        for (int rp = 0; rp < 16; ++rp){
            int idx = rp*256 + t;
            int c = idx >> 6, mm2 = idx & 63;
            float v = bf2f(yb[(size_t)c*MM + m_base + mm2]);
            float t1 = (v - prm[c*2]) * prm[c*2 + 1];
            Xt[c][mm2] = fmaxf(fmaf(t1, gg[c], bt[c]), 0.f);
        }
        __syncthreads();
        float acc[8][4] = {};
#pragma unroll
        for (int c = 0; c < 64; ++c){
            float4 w0v = *(const float4*)&Wt[c][i*8];
            float4 w1v = *(const float4*)&Wt[c][i*8 + 4];
            float4 xv  = *(const float4*)&Xt[c][jj*4];
            float wr[8] = {w0v.x, w0v.y, w0v.z, w0v.w, w1v.x, w1v.y, w1v.z, w1v.w};
            float xr[4] = {xv.x, xv.y, xv.z, xv.w};
#pragma unroll
            for (int a = 0; a < 8; ++a)
#pragma unroll
                for (int q = 0; q < 4; ++q) acc[a][q] = fmaf(wr[a], xr[q], acc[a][q]);
        }
#pragma unroll
        for (int oi = 0; oi < 8; ++oi){
            float bb = bias[i*8 + oi];
#pragma unroll
            for (int q = 0; q < 4; ++q){
                float v = acc[oi][q] + bb;
                s1[oi] += v;
                s2[oi] += (double)v * v;
            }
        }
    }
#pragma unroll
    for (int oi = 0; oi < 8; ++oi){
#pragma unroll
        for (int off = 1; off < 16; off <<= 1){
            s1[oi] += __shfl_xor(s1[oi], off);
            s2[oi] += __shfl_xor(s2[oi], off);
        }
    }
    if (jj == 0){
#pragma unroll
        for (int oi = 0; oi < 8; ++oi){
            int o = i*8 + oi;
            atomicAdd(&stats[o*2 + 0], s1[oi]);
            atomicAdd(&stats[o*2 + 1], s2[oi]);
        }
    }
}

// ---------------------------------------------------------------------------
// 9) final: recompute layer3 GEMM, bn3+relu, max over K -> out1 [B][128][S]
// ---------------------------------------------------------------------------
__global__ __launch_bounds__(256) void k_final(const unsigned short* __restrict__ yb,
                                               const float* __restrict__ prm2,
                                               const float* __restrict__ g1c,
                                               const float* __restrict__ bt1c,
                                               const float* __restrict__ w,
                                               const float* __restrict__ bias,
                                               const float* __restrict__ prm3,
                                               const float* __restrict__ g2c,
                                               const float* __restrict__ bt2c,
                                               float* __restrict__ out1)
{
    __shared__ float Wt[64][128];
    __shared__ float Xt[64][68];
    int t = threadIdx.x;
    int m_base = blockIdx.x * 64;
    for (int i = t; i < 8192; i += 256){
        int o = i >> 6, c = i & 63;
        Wt[c][o] = w[i];
    }
#pragma unroll
    for (int rp = 0; rp < 16; ++rp){
        int idx = rp*256 + t;
        int c = idx >> 6, mm2 = idx & 63;
        float v = bf2f(yb[(size_t)c*MM + m_base + mm2]);
        float t1 = (v - prm2[c*2]) * prm2[c*2 + 1];
        Xt[c][mm2] = fmaxf(fmaf(t1, g1c[c], bt1c[c]), 0.f);
    }
    __syncthreads();
    int i = t >> 4, jj = t & 15;
    float acc[8][4] = {};
#pragma unroll
    for (int c = 0; c < 64; ++c){
        float4 w0v = *(const float4*)&Wt[c][i*8];
        float4 w1v = *(const float4*)&Wt[c][i*8 + 4];
        float4 xv  = *(const float4*)&Xt[c][jj*4];
        float wr[8] = {w0v.x, w0v.y, w0v.z, w0v.w, w1v.x, w1v.y, w1v.z, w1v.w};
        float xr[4] = {xv.x, xv.y, xv.z, xv.w};
#pragma unroll
        for (int a = 0; a < 8; ++a)
#pragma unroll
            for (int q = 0; q < 4; ++q) acc[a][q] = fmaf(wr[a], xr[q], acc[a][q]);
    }
    float mx[8];
#pragma unroll
    for (int oi = 0; oi < 8; ++oi){
        int o = i*8 + oi;
        float bb = bias[o];
        float mu = prm3[o*2], inv = prm3[o*2 + 1], gv = g2c[o], bv = bt2c[o];
        float m = 0.f;   // relu'd values >= 0
#pragma unroll
        for (int q = 0; q < 4; ++q){
            float v = acc[oi][q] + bb;
            float r = fmaxf(fmaf((v - mu) * inv, gv, bv), 0.f);
            m = fmaxf(m, r);
        }
        mx[oi] = m;
    }
#pragma unroll
    for (int oi = 0; oi < 8; ++oi){
#pragma unroll
        for (int off = 1; off < 8; off <<= 1)
            mx[oi] = fmaxf(mx[oi], __shfl_xor(mx[oi], off));
    }
    if ((jj & 7) == 0){
        int rg = (m_base >> 5) + (jj >> 3);   // global row b*S+s
        int b = rg >> 10, s = rg & 1023;
#pragma unroll
        for (int oi = 0; oi < 8; ++oi)
            out1[(size_t)b*131072 + (size_t)(i*8 + oi)*1024 + s] = mx[oi];
    }
}

// ---------------------------------------------------------------------------
extern "C" void kernel_launch(void* const* d_in, const int* in_sizes, int n_in,
                              void* d_out, int out_size, void* d_ws, size_t ws_size,
                              hipStream_t stream)
{
    const float* xyz  = (const float*)d_in[0];
    const float* feat = (const float*)d_in[1];
    const float* w0 = (const float*)d_in[2];  const float* b0  = (const float*)d_in[3];
    const float* g0 = (const float*)d_in[4];  const float* bt0 = (const float*)d_in[5];
    const float* w1 = (const float*)d_in[6];  const float* b1  = (const float*)d_in[7];
    const float* g1 = (const float*)d_in[8];  const float* bt1 = (const float*)d_in[9];
    const float* w2 = (const float*)d_in[10]; const float* b2  = (const float*)d_in[11];
    const float* g2 = (const float*)d_in[12]; const float* bt2 = (const float*)d_in[13];

    float* out0 = (float*)d_out;
    float* out1 = (float*)d_out + 49152;
    float* out2 = (float*)d_out + 49152 + 2097152;

    if (ws_size < WS_NEED){
        k_fail<<<(out_size + 255)/256, 256, 0, stream>>>((float*)d_out, out_size);
        return;
    }

    char* ws = (char*)d_ws;
    double* stats = (double*)(ws + WS_STATS);
    float* params = (float*)(ws + WS_PARAMS);
    int*   fpsidx = (int*)(ws + WS_FPSIDX);
    float* cent   = (float*)(ws + WS_CENT);
    int*   knn    = (int*)(ws + WS_KNN);
    float* comb   = (float*)(ws + WS_COMB);
    unsigned short* yb = (unsigned short*)(ws + WS_YB);

    k_zstats<<<1,    256, 0, stream>>>(stats);
    k_build <<<256,  256, 0, stream>>>(xyz, feat, comb);
    k_fps   <<<16,   512, 0, stream>>>(comb, fpsidx);
    k_gather<<<64,   256, 0, stream>>>(comb, fpsidx, cent, out0, out2);
    k_knn   <<<4096, 256, 0, stream>>>(comb, cent, knn);
    k_l1    <<<8192, 256, 0, stream>>>(comb, cent, knn, w0, b0, yb);
    k_stats <<<512,  256, 0, stream>>>(yb, stats);
    k_affine<<<1,    128, 0, stream>>>(stats, params, 64);
    k_l2    <<<8192, 256, 0, stream>>>(yb, params, g0, bt0, w1, b1);
    k_stats <<<512,  256, 0, stream>>>(yb, stats + 256);
    k_affine<<<1,    128, 0, stream>>>(stats + 256, params + 256, 64);
    k_l3s   <<<512,  256, 0, stream>>>(yb, params + 256, g1, bt1, w2, b2, stats + 512);
    k_affine<<<1,    128, 0, stream>>>(stats + 512, params + 512, 128);
    k_final <<<8192, 256, 0, stream>>>(yb, params + 256, g1, bt1, w2, b2,
                                       params + 512, g2, bt2, out1);
}

// Round 5
// 2934.546 us; speedup vs baseline: 1.1449x; 1.0403x over previous
//
#include <hip/hip_runtime.h>

#define BB 16
#define NN 4096
#define DFEAT 20
#define SS 1024
#define KK 32
#define MM (BB*SS*KK)   // 524288

// ---- workspace layout (bytes), total ~73.6 MB ----
#define WS_STATS   0ull          // 8192   (1024 doubles: 3 layers x up to 256ch x {s1,s2})
#define WS_PARAMS  8192ull       // 4096   (floats: layer L at +L*256 floats: {mu,inv} per ch)
#define WS_FPSIDX  12288ull      // 65536
#define WS_CENT    81920ull      // 1572864  ([B*S][24] gathered combined rows)
#define WS_KNN     1654784ull    // 2097152  ([B*S][32] int)
#define WS_COMB    3751936ull    // 6291456  ([B*N][24] fp32, ch23 = 0 pad)
#define WS_YB      10043392ull   // 67108864 (bf16 [64][M]; y1 then overwritten in-place by y2)
#define WS_NEED    77152256ull

static __device__ __forceinline__ unsigned short f2bf(float f){
    unsigned u = __float_as_uint(f);
    unsigned r = (u + 0x7FFFu + ((u >> 16) & 1u)) >> 16;
    return (unsigned short)r;
}
static __device__ __forceinline__ float bf2f(unsigned short v){
    return __uint_as_float((unsigned)v << 16);
}
// pin a value into a VGPR: empty asm "redefines" it so the compiler cannot
// rematerialize it from memory (forces register residency of the FPS points)
static __device__ __forceinline__ void pinv(float& x){
    asm volatile("" : "+v"(x));
}

// ---------------------------------------------------------------------------
// 0) zero the stats area (1024 doubles)
// ---------------------------------------------------------------------------
__global__ void k_zstats(double* __restrict__ stats){
    int t = threadIdx.x;
#pragma unroll
    for (int i = 0; i < 4; ++i) stats[i*256 + t] = 0.0;
}

// fallback when ws is too small: zero d_out so the harness fails cleanly
__global__ void k_fail(float* __restrict__ out, int n){
    int i = blockIdx.x * 256 + threadIdx.x;
    if (i < n) out[i] = 0.f;
}

// ---------------------------------------------------------------------------
// 1) build combined [B][N][24] (ch23 = 0 pad)
// ---------------------------------------------------------------------------
__global__ __launch_bounds__(256) void k_build(const float* __restrict__ xyz,
                                               const float* __restrict__ feat,
                                               float* __restrict__ comb)
{
    int idx = blockIdx.x * 256 + threadIdx.x;   // over B*N = 65536
    int b = idx >> 12, j = idx & 4095;
    float c[24];
    c[0] = xyz[((size_t)b*3 + 0)*NN + j];
    c[1] = xyz[((size_t)b*3 + 1)*NN + j];
    c[2] = xyz[((size_t)b*3 + 2)*NN + j];
    const float* f = feat + ((size_t)b*NN + j)*DFEAT;
#pragma unroll
    for (int d = 0; d < 20; ++d) c[3+d] = f[d];
    c[23] = 0.f;
    float* out = comb + (size_t)idx * 24;
#pragma unroll
    for (int q = 0; q < 6; ++q)
        ((float4*)out)[q] = make_float4(c[4*q], c[4*q+1], c[4*q+2], c[4*q+3]);
}

// ---------------------------------------------------------------------------
// 2) FPS v4: R4's one-barrier structure + register-pinned points.
//    23 used channels x 8 pts = 184 VGPRs pinned via empty asm; iteration
//    arithmetic is instruction-identical to R4 (ORDER IS LOAD-BEARING).
// ---------------------------------------------------------------------------
__global__ __launch_bounds__(512, 2) void k_fps(const float* __restrict__ comb,
                                                int* __restrict__ fpsidx)
{
    int b = blockIdx.x, t = threadIdx.x;
    const float* C = comb + (size_t)b * NN * 24;
    float pt[8][24];
    float dist[8];
#pragma unroll
    for (int p = 0; p < 8; ++p){
        const float4* r = (const float4*)(C + (size_t)(t + 512*p) * 24);
#pragma unroll
        for (int q = 0; q < 6; ++q){
            float4 v = r[q];
            pt[p][4*q] = v.x; pt[p][4*q+1] = v.y; pt[p][4*q+2] = v.z; pt[p][4*q+3] = v.w;
        }
        dist[p] = 1e10f;
    }
#pragma unroll
    for (int p = 0; p < 8; ++p)
#pragma unroll
        for (int q = 0; q < 23; ++q) pinv(pt[p][q]);   // ch23 unused -> dies

    __shared__ unsigned long long wkey[2][8];
    int lane = t & 63, w = t >> 6;
    int far = 0;
    for (int s = 0; s < SS; ++s){
        if (t == 0) fpsidx[b*SS + s] = far;
        const float4* crow = (const float4*)(C + (size_t)far * 24);
        float cc[24];
#pragma unroll
        for (int q = 0; q < 6; ++q){
            float4 cv = crow[q];          // uniform address: broadcast load
            cc[4*q] = cv.x; cc[4*q+1] = cv.y; cc[4*q+2] = cv.z; cc[4*q+3] = cv.w;
        }
        unsigned long long best = 0;
#pragma unroll
        for (int p = 0; p < 8; ++p){
            float d0 = pt[p][0] - cc[0];
            float acc = d0 * d0;
#pragma unroll
            for (int q = 1; q < 23; ++q){
                float dd = pt[p][q] - cc[q];
                acc = fmaf(dd, dd, acc);
            }
            dist[p] = fminf(dist[p], acc);
            unsigned long long key = ((unsigned long long)__float_as_uint(dist[p]) << 32)
                                   | (unsigned long long)(0xFFFFFFFFu - (unsigned)(t + 512*p));
            best = best > key ? best : key;
        }
#pragma unroll
        for (int off = 32; off > 0; off >>= 1){
            unsigned long long o = __shfl_xor(best, off);
            best = best > o ? best : o;
        }
        int par = s & 1;
        if (lane == 0) wkey[par][w] = best;
        __syncthreads();
        // double-buffered: next write to this buffer is 2 iters (1 barrier) away
        unsigned long long k2 = wkey[par][lane & 7];
#pragma unroll
        for (int off = 1; off < 8; off <<= 1){
            unsigned long long o = __shfl_xor(k2, off);
            k2 = k2 > o ? k2 : o;
        }
        far = (int)(0xFFFFFFFFu - (unsigned)(k2 & 0xFFFFFFFFull));
    }
}

// ---------------------------------------------------------------------------
// 3) gather centroids + outputs 0 and 2 (exact gathers)
// ---------------------------------------------------------------------------
__global__ __launch_bounds__(256) void k_gather(const float* __restrict__ comb,
                                                const int* __restrict__ fpsidx,
                                                float* __restrict__ cent,
                                                float* __restrict__ out0,
                                                float* __restrict__ out2)
{
    int idx = blockIdx.x * 256 + threadIdx.x;   // over B*S = 16384
    int b = idx >> 10, s = idx & 1023;
    int j = fpsidx[idx];
    const float* row = comb + ((size_t)b*NN + j) * 24;
    float* cr = cent + (size_t)idx * 24;
#pragma unroll
    for (int q = 0; q < 6; ++q) ((float4*)cr)[q] = ((const float4*)row)[q];
#pragma unroll
    for (int c = 0; c < 3; ++c) out0[((size_t)b*3 + c)*SS + s] = row[c];
    float* o2 = out2 + (size_t)idx * 20;
#pragma unroll
    for (int d = 0; d < 20; ++d) o2[d] = row[3 + d];
}

// ---------------------------------------------------------------------------
// 4) KNN v2: fp64 distance computation (validated R2/R4 numerics) downcast to
//    fp32 orderable u32 keys -> u[64] (no fp64 array, no spill). Exact top-32
//    SET via 32-step binary search for the 32nd value + ballot compaction
//    with ascending-index tie-break (order within the 32 is free downstream:
//    BN stats and max-over-K are permutation invariant).
// ---------------------------------------------------------------------------
__global__ __launch_bounds__(256) void k_knn(const float* __restrict__ comb,
                                             const float* __restrict__ cent,
                                             int* __restrict__ knn)
{
    int w = threadIdx.x >> 6, lane = threadIdx.x & 63;
    int r = blockIdx.x * 4 + w;     // row over B*S
    int b = r >> 10;
    const float* crow = cent + (size_t)r * 24;
    const float* P0 = comb + (size_t)b * NN * 24;
    double cc[24];
#pragma unroll
    for (int q = 0; q < 24; ++q) cc[q] = (double)crow[q];
    unsigned u[64];
#pragma unroll
    for (int k = 0; k < 64; ++k){
        int j = k*64 + lane;
        const float4* pr = (const float4*)(P0 + (size_t)j * 24);
        double acc = 0.0;
#pragma unroll
        for (int q = 0; q < 6; ++q){
            float4 v = pr[q];
            double d0 = (double)v.x - cc[4*q];
            double d1 = (double)v.y - cc[4*q+1];
            double d2 = (double)v.z - cc[4*q+2];
            double d3 = (double)v.w - cc[4*q+3];
            acc += d0*d0; acc += d1*d1; acc += d2*d2; acc += d3*d3;
        }
        u[k] = __float_as_uint((float)acc);   // >=0 -> bits are monotone
    }
    // binary search for T = value of the 32nd smallest key
    unsigned lo = 0u, hi = 0xFFFFFFFFu;
    for (int it = 0; it < 32; ++it){
        unsigned mid = lo + ((hi - lo) >> 1);
        int cnt = 0;
#pragma unroll
        for (int k = 0; k < 64; ++k) cnt += (u[k] <= mid) ? 1 : 0;
#pragma unroll
        for (int off = 32; off > 0; off >>= 1) cnt += __shfl_xor(cnt, off);
        if (cnt >= KK) hi = mid; else lo = mid + 1;
    }
    unsigned T = lo;
    int* orow = knn + (size_t)r * KK;
    unsigned long long lmask = (1ull << lane) - 1ull;
    int pos = 0;
#pragma unroll
    for (int k = 0; k < 64; ++k){
        bool lt = (u[k] < T);
        unsigned long long mk = __ballot(lt);
        if (lt) orow[pos + __popcll(mk & lmask)] = k*64 + lane;
        pos += __popcll(mk);
    }
#pragma unroll
    for (int k = 0; k < 64; ++k){
        if (pos >= KK) break;
        bool eq = (u[k] == T);
        unsigned long long mk = __ballot(eq);
        int rk = __popcll(mk & lmask);
        if (eq && (pos + rk) < KK) orow[pos + rk] = k*64 + lane;
        pos += __popcll(mk);
    }
}

// ---------------------------------------------------------------------------
// 5) layer 1: gather+normalize -> 24ch, GEMM 24->64, +bias -> yb bf16 [64][M]
// ---------------------------------------------------------------------------
__global__ __launch_bounds__(256) void k_l1(const float* __restrict__ comb,
                                            const float* __restrict__ cent,
                                            const int* __restrict__ knn,
                                            const float* __restrict__ w0,
                                            const float* __restrict__ b0,
                                            unsigned short* __restrict__ yb)
{
    __shared__ float Wt[24][64];
    __shared__ float Xt[24][68];
    int t = threadIdx.x;
    int m_base = blockIdx.x * 64;
    for (int i = t; i < 1536; i += 256){
        int o = i / 24, c = i - o*24;
        Wt[c][o] = w0[i];
    }
    {
        int sm = t & 63, g = t >> 6;
        int m = m_base + sm;
        int b = m >> 15;
        int row = m >> 5;
        int j = knn[m];
        const float* P  = comb + ((size_t)b*NN + j) * 24;
        const float* Cc = cent + (size_t)row * 24;
        if (g == 0){
            float dx = P[0]-Cc[0], dy = P[1]-Cc[1], dz = P[2]-Cc[2];
            Xt[0][sm] = dx; Xt[1][sm] = dy; Xt[2][sm] = dz;
            float n2 = dx*dx; n2 = fmaf(dy, dy, n2); n2 = fmaf(dz, dz, n2);
            Xt[3][sm] = sqrtf(fmaxf(n2, 1e-12f));
            Xt[4][sm] = P[3] - Cc[3];
            Xt[5][sm] = P[4] - Cc[4];
        } else {
#pragma unroll
            for (int cq = 0; cq < 6; ++cq){
                int c = 6*g + cq;
                Xt[c][sm] = P[c-1] - Cc[c-1];
            }
        }
    }
    __syncthreads();
    int i = t >> 4, jj = t & 15;
    float acc[4][4] = {};
#pragma unroll
    for (int c = 0; c < 24; ++c){
        float4 wv = *(const float4*)&Wt[c][i*4];
        float4 xv = *(const float4*)&Xt[c][jj*4];
        float wr[4] = {wv.x, wv.y, wv.z, wv.w};
        float xr[4] = {xv.x, xv.y, xv.z, xv.w};
#pragma unroll
        for (int a = 0; a < 4; ++a)
#pragma unroll
            for (int q = 0; q < 4; ++q) acc[a][q] = fmaf(wr[a], xr[q], acc[a][q]);
    }
#pragma unroll
    for (int oi = 0; oi < 4; ++oi){
        int o = i*4 + oi;
        float bb = b0[o];
        ushort4 rv;
        rv.x = f2bf(acc[oi][0]+bb); rv.y = f2bf(acc[oi][1]+bb);
        rv.z = f2bf(acc[oi][2]+bb); rv.w = f2bf(acc[oi][3]+bb);
        *(ushort4*)&yb[(size_t)o*MM + m_base + jj*4] = rv;
    }
}

// ---------------------------------------------------------------------------
// 6) per-channel sum/sumsq (fp64) over bf16 [64][M]
// ---------------------------------------------------------------------------
__global__ __launch_bounds__(256) void k_stats(const unsigned short* __restrict__ y,
                                               double* __restrict__ stats)
{
    const int chunks = 8;
    int c = blockIdx.x / chunks, ch = blockIdx.x % chunks;
    size_t base = (size_t)c * MM + (size_t)ch * (MM / chunks);
    double s1 = 0.0, s2 = 0.0;
    const unsigned short* p = y + base;
    for (int i = threadIdx.x; i < MM/chunks; i += 256){
        float v = bf2f(p[i]);
        s1 += v; s2 += (double)v * v;
    }
#pragma unroll
    for (int off = 32; off > 0; off >>= 1){
        s1 += __shfl_xor(s1, off);
        s2 += __shfl_xor(s2, off);
    }
    __shared__ double ps1[4], ps2[4];
    int w = threadIdx.x >> 6, lane = threadIdx.x & 63;
    if (lane == 0){ ps1[w] = s1; ps2[w] = s2; }
    __syncthreads();
    if (threadIdx.x == 0){
        atomicAdd(&stats[c*2 + 0], ps1[0]+ps1[1]+ps1[2]+ps1[3]);
        atomicAdd(&stats[c*2 + 1], ps2[0]+ps2[1]+ps2[2]+ps2[3]);
    }
}

__global__ void k_affine(const double* __restrict__ stats, float* __restrict__ params, int C)
{
    int c = threadIdx.x;
    if (c < C){
        double mu = stats[c*2] / (double)MM;
        double var = stats[c*2 + 1] / (double)MM - mu*mu;
        params[c*2 + 0] = (float)mu;
        params[c*2 + 1] = (float)(1.0 / sqrt(var + 1e-5));
    }
}

// ---------------------------------------------------------------------------
// 7) layer 2 IN-PLACE: bn1+relu(yb) -> GEMM 64->64 -> yb (same tile, bf16)
// ---------------------------------------------------------------------------
__global__ __launch_bounds__(256) void k_l2(unsigned short* __restrict__ yb,
                                            const float* __restrict__ prm,
                                            const float* __restrict__ gg,
                                            const float* __restrict__ bt,
                                            const float* __restrict__ w,
                                            const float* __restrict__ bias)
{
    __shared__ float Wt[64][64];
    __shared__ float Xt[64][68];
    int t = threadIdx.x;
    int m_base = blockIdx.x * 64;
    for (int i = t; i < 4096; i += 256){
        int o = i >> 6, c = i & 63;
        Wt[c][o] = w[i];
    }
#pragma unroll
    for (int rp = 0; rp < 16; ++rp){
        int idx = rp*256 + t;
        int c = idx >> 6, mm2 = idx & 63;
        float v = bf2f(yb[(size_t)c*MM + m_base + mm2]);
        float t1 = (v - prm[c*2]) * prm[c*2 + 1];
        Xt[c][mm2] = fmaxf(fmaf(t1, gg[c], bt[c]), 0.f);
    }
    __syncthreads();
    int i = t >> 4, jj = t & 15;
    float acc[4][4] = {};
#pragma unroll
    for (int c = 0; c < 64; ++c){
        float4 wv = *(const float4*)&Wt[c][i*4];
        float4 xv = *(const float4*)&Xt[c][jj*4];
        float wr[4] = {wv.x, wv.y, wv.z, wv.w};
        float xr[4] = {xv.x, xv.y, xv.z, xv.w};
#pragma unroll
        for (int a = 0; a < 4; ++a)
#pragma unroll
            for (int q = 0; q < 4; ++q) acc[a][q] = fmaf(wr[a], xr[q], acc[a][q]);
    }
    // all reads of this tile happened before the barrier above -> in-place safe
#pragma unroll
    for (int oi = 0; oi < 4; ++oi){
        int o = i*4 + oi;
        float bb = bias[o];
        ushort4 rv;
        rv.x = f2bf(acc[oi][0]+bb); rv.y = f2bf(acc[oi][1]+bb);
        rv.z = f2bf(acc[oi][2]+bb); rv.w = f2bf(acc[oi][3]+bb);
        *(ushort4*)&yb[(size_t)o*MM + m_base + jj*4] = rv;
    }
}

// ---------------------------------------------------------------------------
// 8) layer 3 stats pass: bn2+relu(yb) -> GEMM 64->128 in regs -> stats3 only
// ---------------------------------------------------------------------------
__global__ __launch_bounds__(256) void k_l3s(const unsigned short* __restrict__ yb,
                                             const float* __restrict__ prm,
                                             const float* __restrict__ gg,
                                             const float* __restrict__ bt,
                                             const float* __restrict__ w,
                                             const float* __restrict__ bias,
                                             double* __restrict__ stats)
{
    __shared__ float Wt[64][128];
    __shared__ float Xt[64][68];
    int t = threadIdx.x;
    for (int i = t; i < 8192; i += 256){
        int o = i >> 6, c = i & 63;
        Wt[c][o] = w[i];
    }
    int i = t >> 4, jj = t & 15;
    double s1[8] = {}, s2[8] = {};
    for (int tt = 0; tt < 16; ++tt){
        int m_base = (blockIdx.x * 16 + tt) * 64;
        __syncthreads();
#pragma unroll
        for (int rp = 0; rp < 16; ++rp){
            int idx = rp*256 + t;
            int c = idx >> 6, mm2 = idx & 63;
            float v = bf2f(yb[(size_t)c*MM + m_base + mm2]);
            float t1 = (v - prm[c*2]) * prm[c*2 + 1];
            Xt[c][mm2] = fmaxf(fmaf(t1, gg[c], bt[c]), 0.f);
        }
        __syncthreads();
        float acc[8][4] = {};
#pragma unroll
        for (int c = 0; c < 64; ++c){
            float4 w0v = *(const float4*)&Wt[c][i*8];
            float4 w1v = *(const float4*)&Wt[c][i*8 + 4];
            float4 xv  = *(const float4*)&Xt[c][jj*4];
            float wr[8] = {w0v.x, w0v.y, w0v.z, w0v.w, w1v.x, w1v.y, w1v.z, w1v.w};
            float xr[4] = {xv.x, xv.y, xv.z, xv.w};
#pragma unroll
            for (int a = 0; a < 8; ++a)
#pragma unroll
                for (int q = 0; q < 4; ++q) acc[a][q] = fmaf(wr[a], xr[q], acc[a][q]);
        }
#pragma unroll
        for (int oi = 0; oi < 8; ++oi){
            float bb = bias[i*8 + oi];
#pragma unroll
            for (int q = 0; q < 4; ++q){
                float v = acc[oi][q] + bb;
                s1[oi] += v;
                s2[oi] += (double)v * v;
            }
        }
    }
#pragma unroll
    for (int oi = 0; oi < 8; ++oi){
#pragma unroll
        for (int off = 1; off < 16; off <<= 1){
            s1[oi] += __shfl_xor(s1[oi], off);
            s2[oi] += __shfl_xor(s2[oi], off);
        }
    }
    if (jj == 0){
#pragma unroll
        for (int oi = 0; oi < 8; ++oi){
            int o = i*8 + oi;
            atomicAdd(&stats[o*2 + 0], s1[oi]);
            atomicAdd(&stats[o*2 + 1], s2[oi]);
        }
    }
}

// ---------------------------------------------------------------------------
// 9) final: recompute layer3 GEMM, bn3+relu, max over K -> out1 [B][128][S]
// ---------------------------------------------------------------------------
__global__ __launch_bounds__(256) void k_final(const unsigned short* __restrict__ yb,
                                               const float* __restrict__ prm2,
                                               const float* __restrict__ g1c,
                                               const float* __restrict__ bt1c,
                                               const float* __restrict__ w,
                                               const float* __restrict__ bias,
                                               const float* __restrict__ prm3,
                                               const float* __restrict__ g2c,
                                               const float* __restrict__ bt2c,
                                               float* __restrict__ out1)
{
    __shared__ float Wt[64][128];
    __shared__ float Xt[64][68];
    int t = threadIdx.x;
    int m_base = blockIdx.x * 64;
    for (int i = t; i < 8192; i += 256){
        int o = i >> 6, c = i & 63;
        Wt[c][o] = w[i];
    }
#pragma unroll
    for (int rp = 0; rp < 16; ++rp){
        int idx = rp*256 + t;
        int c = idx >> 6, mm2 = idx & 63;
        float v = bf2f(yb[(size_t)c*MM + m_base + mm2]);
        float t1 = (v - prm2[c*2]) * prm2[c*2 + 1];
        Xt[c][mm2] = fmaxf(fmaf(t1, g1c[c], bt1c[c]), 0.f);
    }
    __syncthreads();
    int i = t >> 4, jj = t & 15;
    float acc[8][4] = {};
#pragma unroll
    for (int c = 0; c < 64; ++c){
        float4 w0v = *(const float4*)&Wt[c][i*8];
        float4 w1v = *(const float4*)&Wt[c][i*8 + 4];
        float4 xv  = *(const float4*)&Xt[c][jj*4];
        float wr[8] = {w0v.x, w0v.y, w0v.z, w0v.w, w1v.x, w1v.y, w1v.z, w1v.w};
        float xr[4] = {xv.x, xv.y, xv.z, xv.w};
#pragma unroll
        for (int a = 0; a < 8; ++a)
#pragma unroll
            for (int q = 0; q < 4; ++q) acc[a][q] = fmaf(wr[a], xr[q], acc[a][q]);
    }
    float mx[8];
#pragma unroll
    for (int oi = 0; oi < 8; ++oi){
        int o = i*8 + oi;
        float bb = bias[o];
        float mu = prm3[o*2], inv = prm3[o*2 + 1], gv = g2c[o], bv = bt2c[o];
        float m = 0.f;   // relu'd values >= 0
#pragma unroll
        for (int q = 0; q < 4; ++q){
            float v = acc[oi][q] + bb;
            float r = fmaxf(fmaf((v - mu) * inv, gv, bv), 0.f);
            m = fmaxf(m, r);
        }
        mx[oi] = m;
    }
#pragma unroll
    for (int oi = 0; oi < 8; ++oi){
#pragma unroll
        for (int off = 1; off < 8; off <<= 1)
            mx[oi] = fmaxf(mx[oi], __shfl_xor(mx[oi], off));
    }
    if ((jj & 7) == 0){
        int rg = (m_base >> 5) + (jj >> 3);   // global row b*S+s
        int b = rg >> 10, s = rg & 1023;
#pragma unroll
        for (int oi = 0; oi < 8; ++oi)
            out1[(size_t)b*131072 + (size_t)(i*8 + oi)*1024 + s] = mx[oi];
    }
}

// ---------------------------------------------------------------------------
extern "C" void kernel_launch(void* const* d_in, const int* in_sizes, int n_in,
                              void* d_out, int out_size, void* d_ws, size_t ws_size,
                              hipStream_t stream)
{
    const float* xyz  = (const float*)d_in[0];
    const float* feat = (const float*)d_in[1];
    const float* w0 = (const float*)d_in[2];  const float* b0  = (const float*)d_in[3];
    const float* g0 = (const float*)d_in[4];  const float* bt0 = (const float*)d_in[5];
    const float* w1 = (const float*)d_in[6];  const float* b1  = (const float*)d_in[7];
    const float* g1 = (const float*)d_in[8];  const float* bt1 = (const float*)d_in[9];
    const float* w2 = (const float*)d_in[10]; const float* b2  = (const float*)d_in[11];
    const float* g2 = (const float*)d_in[12]; const float* bt2 = (const float*)d_in[13];

    float* out0 = (float*)d_out;
    float* out1 = (float*)d_out + 49152;
    float* out2 = (float*)d_out + 49152 + 2097152;

    if (ws_size < WS_NEED){
        k_fail<<<(out_size + 255)/256, 256, 0, stream>>>((float*)d_out, out_size);
        return;
    }

    char* ws = (char*)d_ws;
    double* stats = (double*)(ws + WS_STATS);
    float* params = (float*)(ws + WS_PARAMS);
    int*   fpsidx = (int*)(ws + WS_FPSIDX);
    float* cent   = (float*)(ws + WS_CENT);
    int*   knn    = (int*)(ws + WS_KNN);
    float* comb   = (float*)(ws + WS_COMB);
    unsigned short* yb = (unsigned short*)(ws + WS_YB);

    k_zstats<<<1,    256, 0, stream>>>(stats);
    k_build <<<256,  256, 0, stream>>>(xyz, feat, comb);
    k_fps   <<<16,   512, 0, stream>>>(comb, fpsidx);
    k_gather<<<64,   256, 0, stream>>>(comb, fpsidx, cent, out0, out2);
    k_knn   <<<4096, 256, 0, stream>>>(comb, cent, knn);
    k_l1    <<<8192, 256, 0, stream>>>(comb, cent, knn, w0, b0, yb);
    k_stats <<<512,  256, 0, stream>>>(yb, stats);
    k_affine<<<1,    128, 0, stream>>>(stats, params, 64);
    k_l2    <<<8192, 256, 0, stream>>>(yb, params, g0, bt0, w1, b1);
    k_stats <<<512,  256, 0, stream>>>(yb, stats + 256);
    k_affine<<<1,    128, 0, stream>>>(stats + 256, params + 256, 64);
    k_l3s   <<<512,  256, 0, stream>>>(yb, params + 256, g1, bt1, w2, b2, stats + 512);
    k_affine<<<1,    128, 0, stream>>>(stats + 512, params + 512, 128);
    k_final <<<8192, 256, 0, stream>>>(yb, params + 256, g1, bt1, w2, b2,
                                       params + 512, g2, bt2, out1);
}